// Round 1
// 157.894 us; speedup vs baseline: 1.0991x; 1.0991x over previous
//
#include <hip/hip_runtime.h>

#define DIMN 32
#define HD   32
#define FN   16
#define FE   8
#define NG   64
#define NPB1 16   // nodes per block, K1
#define NPB3 64   // nodes per block, K3 (8 consecutive nodes per 32-lane subgroup)

// K1: per-node precompute + workspace zeroing.
__global__ __launch_bounds__(256) void k1_node_pre(
    const float* __restrict__ x, const float* __restrict__ lin0_w,
    const float* __restrict__ lin0_b, const float* __restrict__ nn_w,
    const float* __restrict__ nn_b,
    float* __restrict__ outn, float* __restrict__ G, float* __restrict__ bmsg,
    float* __restrict__ agg, float* __restrict__ u, int N)
{
    __shared__ float s_nnw[DIMN * HD * FE];  // 32 KB
    __shared__ float s_nnb[DIMN * HD];       // 4 KB
    __shared__ float s_l0w[DIMN * FN];
    __shared__ float s_l0b[DIMN];
    __shared__ float s_out[NPB1 * DIMN];     // 2 KB

    const int tid = threadIdx.x;
    for (int i = tid; i < DIMN * HD * FE; i += 256) s_nnw[i] = nn_w[i];
    for (int i = tid; i < DIMN * HD; i += 256)      s_nnb[i] = nn_b[i];
    for (int i = tid; i < DIMN * FN; i += 256)      s_l0w[i] = lin0_w[i];
    if (tid < DIMN) s_l0b[tid] = lin0_b[tid];

    const int n0 = blockIdx.x * NPB1;

    // Zero agg slice (replaces hipMemsetAsync); first 8 blocks zero u.
    {
        const int a0 = n0 * HD;
        const int a1 = min((n0 + NPB1) * HD, N * HD);
        for (int i = a0 + tid; i < a1; i += 256) agg[i] = 0.f;
        if (blockIdx.x < (NG * HD) / 256) u[blockIdx.x * 256 + tid] = 0.f;
    }
    __syncthreads();

    // Phase A: out for all NPB1 nodes. 8 nodes in parallel per pass.
    #pragma unroll
    for (int pass = 0; pass < 2; ++pass) {
        const int nl = pass * 8 + (tid >> 5);
        const int d  = tid & 31;
        const int n  = n0 + nl;
        if (n < N) {
            float s = s_l0b[d];
            const float* xr = x + (size_t)n * FN;
            #pragma unroll
            for (int j = 0; j < FN; ++j) s = fmaf(xr[j], s_l0w[d * FN + j], s);
            s = fmaxf(s, 0.f);
            s_out[nl * DIMN + d] = s;
            outn[(size_t)n * DIMN + d] = s;
        }
    }
    __syncthreads();

    // Phase B: G rows (s_out broadcast; s_nnw conflict-free; no barriers).
    for (int nl = 0; nl < NPB1; ++nl) {
        const int n = n0 + nl;
        if (n >= N) break;
        float g = 0.f;
        #pragma unroll 8
        for (int d = 0; d < DIMN; ++d)
            g = fmaf(s_out[nl * DIMN + d], s_nnw[d * 256 + tid], g);
        G[(size_t)n * 256 + tid] = g;
    }

    // Phase B2: bmsg.
    #pragma unroll
    for (int pass = 0; pass < 2; ++pass) {
        const int nl = pass * 8 + (tid >> 5);
        const int h  = tid & 31;
        const int n  = n0 + nl;
        if (n < N) {
            float b = 0.f;
            #pragma unroll 8
            for (int d = 0; d < DIMN; ++d)
                b = fmaf(s_out[nl * DIMN + d], s_nnb[d * HD + h], b);
            bmsg[(size_t)n * HD + h] = b;
        }
    }
}

// K2: per-edge message + scatter. 32 threads per edge, thread = h. (unchanged)
__global__ __launch_bounds__(256) void k2_edge(
    const int* __restrict__ ei, const float* __restrict__ ea,
    const float* __restrict__ G, const float* __restrict__ bmsg,
    float* __restrict__ agg, int E)
{
    const int t = blockIdx.x * 256 + threadIdx.x;
    const int e = t >> 5;
    const int h = t & 31;
    if (e >= E) return;

    const int src = ei[e];
    const int dst = ei[E + e];

    const float* gp = G + (size_t)src * 256 + h * 8;
    const float4 ga = *(const float4*)(gp);
    const float4 gb = *(const float4*)(gp + 4);
    const float4 e0 = *(const float4*)(ea + (size_t)e * 8);
    const float4 e1 = *(const float4*)(ea + (size_t)e * 8 + 4);

    float acc = bmsg[(size_t)src * HD + h];
    acc = fmaf(e0.x, ga.x, acc);
    acc = fmaf(e0.y, ga.y, acc);
    acc = fmaf(e0.z, ga.z, acc);
    acc = fmaf(e0.w, ga.w, acc);
    acc = fmaf(e1.x, gb.x, acc);
    acc = fmaf(e1.y, gb.y, acc);
    acc = fmaf(e1.z, gb.z, acc);
    acc = fmaf(e1.w, gb.w, acc);

    atomicAdd(agg + (size_t)dst * HD + h, acc);
}

// K3: relu(agg + out@root_w + conv_b); run-length pooled into u (batch sorted).
__global__ __launch_bounds__(256) void k3_node_upd(
    const float* __restrict__ agg, const float* __restrict__ outn,
    const float* __restrict__ root_w, const float* __restrict__ conv_b,
    const int* __restrict__ batch, float* __restrict__ u, int N)
{
    __shared__ float s_rw[DIMN * HD];
    __shared__ float s_cb[HD];
    const int tid = threadIdx.x;
    for (int i = tid; i < DIMN * HD; i += 256) s_rw[i] = root_w[i];
    if (tid < HD) s_cb[tid] = conv_b[tid];
    __syncthreads();

    const int sg   = tid >> 5;
    const int h    = tid & 31;
    const int base = blockIdx.x * NPB3 + sg * (NPB3 / 8);

    float acc  = 0.f;
    int  g_cur = -1;
    #pragma unroll
    for (int i = 0; i < NPB3 / 8; ++i) {
        const int n = base + i;
        if (n >= N) break;

        float v = agg[(size_t)n * HD + h] + s_cb[h];
        const float* orow = outn + (size_t)n * DIMN;
        #pragma unroll 8
        for (int k = 0; k < DIMN; ++k)
            v = fmaf(orow[k], s_rw[k * HD + h], v);
        v = fmaxf(v, 0.f);

        const int g = (int)batch[n];   // uniform within subgroup
        if (g != g_cur) {
            if (g_cur >= 0) atomicAdd(u + (size_t)g_cur * HD + h, acc);
            g_cur = g;
            acc = v;
        } else {
            acc += v;
        }
    }
    if (g_cur >= 0) atomicAdd(u + (size_t)g_cur * HD + h, acc);
}

// K4: head. (unchanged)
__global__ __launch_bounds__(64) void k4_head(
    const float* __restrict__ u, const float* __restrict__ lin1_w,
    const float* __restrict__ lin1_b, const float* __restrict__ lin2_w,
    const float* __restrict__ lin2_b, float* __restrict__ outp)
{
    const int g = threadIdx.x;
    if (g >= NG) return;

    float ur[HD];
    #pragma unroll
    for (int hh = 0; hh < HD; ++hh) ur[hh] = u[(size_t)g * HD + hh];

    float acc = lin2_b[0];
    #pragma unroll
    for (int i = 0; i < 16; ++i) {
        float o = lin1_b[i];
        #pragma unroll
        for (int hh = 0; hh < HD; ++hh)
            o = fmaf(ur[hh], lin1_w[i * HD + hh], o);
        o = fmaxf(o, 0.f);
        acc = fmaf(o, lin2_w[i], acc);
    }
    outp[g] = acc;
}

extern "C" void kernel_launch(void* const* d_in, const int* in_sizes, int n_in,
                              void* d_out, int out_size, void* d_ws, size_t ws_size,
                              hipStream_t stream)
{
    const float* x      = (const float*)d_in[0];
    const int*   ei     = (const int*)  d_in[1];
    const float* ea     = (const float*)d_in[2];
    const int*   batch  = (const int*)  d_in[3];
    const float* lin0_w = (const float*)d_in[4];
    const float* lin0_b = (const float*)d_in[5];
    const float* nn_w   = (const float*)d_in[6];
    const float* nn_b   = (const float*)d_in[7];
    const float* root_w = (const float*)d_in[8];
    const float* conv_b = (const float*)d_in[9];
    const float* lin1_w = (const float*)d_in[10];
    const float* lin1_b = (const float*)d_in[11];
    const float* lin2_w = (const float*)d_in[12];
    const float* lin2_b = (const float*)d_in[13];

    const int N = in_sizes[0] / FN;   // 12500 (same semantics as passing baseline)
    const int E = in_sizes[2] / FE;   // 200000

    float* ws   = (float*)d_ws;
    float* outn = ws;                         // N*32
    float* G    = outn + (size_t)N * DIMN;    // N*256
    float* bmsg = G    + (size_t)N * 256;     // N*32
    float* agg  = bmsg + (size_t)N * DIMN;    // N*32
    float* u    = agg  + (size_t)N * DIMN;    // 64*32

    const int nb1 = (N + NPB1 - 1) / NPB1;    // 782 >= 8, so u zeroing is covered
    k1_node_pre<<<nb1, 256, 0, stream>>>(x, lin0_w, lin0_b, nn_w, nn_b,
                                         outn, G, bmsg, agg, u, N);

    const int nb2 = (E * 32 + 255) / 256;
    k2_edge<<<nb2, 256, 0, stream>>>(ei, ea, G, bmsg, agg, E);

    const int nb3 = (N + NPB3 - 1) / NPB3;    // 196
    k3_node_upd<<<nb3, 256, 0, stream>>>(agg, outn, root_w, conv_b, batch, u, N);

    k4_head<<<1, 64, 0, stream>>>(u, lin1_w, lin1_b, lin2_w, lin2_b, (float*)d_out);
}